// Round 2
// baseline (914.881 us; speedup 1.0000x reference)
//
#include <hip/hip_runtime.h>
#include <hip/hip_bf16.h>

// Problem constants (B=2, T=2048, D=1024, H=16, Dh=64)
#define B_SZ    2
#define T_SEQ   2048
#define D_MODEL 1024
#define N_HEADS 16
#define D_HEAD  64
#define BT      (B_SZ * T_SEQ)   // 4096 rows

typedef unsigned short u16;
typedef __attribute__((ext_vector_type(8))) short  short8;    // 8 bf16 (4 VGPRs)
typedef __attribute__((ext_vector_type(4))) float  floatx4;   // MFMA acc
typedef __attribute__((ext_vector_type(4))) unsigned short ushortx4;

__device__ inline u16 f2b(float f) {
    __hip_bfloat16 h = __float2bfloat16(f);   // RNE
    return *(u16*)&h;
}

// ---------------------------------------------------------------------------
// fp32 -> bf16 conversion, 4 elems/thread (float4 load, 8B store)
// ---------------------------------------------------------------------------
__global__ __launch_bounds__(256) void cvt_kernel(
    const float* __restrict__ in, u16* __restrict__ out, int n4)
{
    const int i = blockIdx.x * 256 + threadIdx.x;
    if (i >= n4) return;
    floatx4 v = ((const floatx4*)in)[i];
    ushortx4 r;
    r[0] = f2b(v[0]); r[1] = f2b(v[1]); r[2] = f2b(v[2]); r[3] = f2b(v[3]);
    ((ushortx4*)out)[i] = r;
}

// ---------------------------------------------------------------------------
// NT GEMM: C[m,n] = sum_k A[m,k] * B[n,k],  A:MxK bf16, B:NxK bf16, C fp32.
// One wave computes 16(m)x64(n). MFMA 16x16x32 bf16.
// A/B frag: [row=lane&15][k=quad*8+j]; C/D: col=lane&15, row=quad*4+reg.
// Grid must supply exactly (M/16)*(N/64) waves.
// ---------------------------------------------------------------------------
__global__ __launch_bounds__(256) void gemm_nt_kernel(
    const u16* __restrict__ A, const u16* __restrict__ B,
    float* __restrict__ C, int M, int N, int K)
{
    const int gw     = (blockIdx.x * 256 + threadIdx.x) >> 6;
    const int lane   = threadIdx.x & 63;
    const int tilesM = M >> 4;
    const int row    = lane & 15;
    const int quad   = lane >> 4;
    const int tm     = gw % tilesM;
    const int tn     = gw / tilesM;

    const u16* Ap = A + (size_t)(tm * 16 + row) * K + quad * 8;
    const u16* Bp = B + (size_t)(tn * 64 + row) * K + quad * 8;

    floatx4 acc0 = {0.f, 0.f, 0.f, 0.f};
    floatx4 acc1 = acc0, acc2 = acc0, acc3 = acc0;

    for (int k = 0; k < K; k += 32) {
        short8 a  = *(const short8*)(Ap + k);
        short8 b0 = *(const short8*)(Bp + k);
        short8 b1 = *(const short8*)(Bp + 16 * K + k);
        short8 b2 = *(const short8*)(Bp + 32 * K + k);
        short8 b3 = *(const short8*)(Bp + 48 * K + k);
        acc0 = __builtin_amdgcn_mfma_f32_16x16x32_bf16(a, b0, acc0, 0, 0, 0);
        acc1 = __builtin_amdgcn_mfma_f32_16x16x32_bf16(a, b1, acc1, 0, 0, 0);
        acc2 = __builtin_amdgcn_mfma_f32_16x16x32_bf16(a, b2, acc2, 0, 0, 0);
        acc3 = __builtin_amdgcn_mfma_f32_16x16x32_bf16(a, b3, acc3, 0, 0, 0);
    }

    #pragma unroll
    for (int rr = 0; rr < 4; ++rr) {
        const int m = tm * 16 + quad * 4 + rr;
        float* Cp = C + (size_t)m * N + tn * 64 + row;
        Cp[0]  = acc0[rr];
        Cp[16] = acc1[rr];
        Cp[32] = acc2[rr];
        Cp[48] = acc3[rr];
    }
}

// ---------------------------------------------------------------------------
// Causal flash attention, scalar fp32 compute (correctness-first baseline).
// Block = 256 threads per (b, h, 64-query tile). qkv fp32 [B,T,3*D]
// (q at +0, k at +D, v at +2D). Output y bf16 [B,T,D].
// ---------------------------------------------------------------------------
__global__ __launch_bounds__(256) void attn_kernel(
    const float* __restrict__ qkv, u16* __restrict__ y)
{
    const int bid = blockIdx.x;
    const int qt  = bid & 31;          // T/64 = 32 query tiles
    const int h   = (bid >> 5) & 15;
    const int b   = bid >> 9;

    __shared__ __align__(16) float Qt[D_HEAD][68];   // Qt[d][q]
    __shared__ __align__(16) float Kt[D_HEAD][68];   // Kt[d][k]
    __shared__ __align__(16) float Vs[64][68];       // Vs[k][d]
    __shared__ __align__(16) float Sc[64][68];       // Sc[k][q] (transposed)
    __shared__ float mS[64], lS[64], aS[64];

    const int t   = threadIdx.x;
    const int lr  = t >> 2;            // 0..63  staging row
    const int lc  = (t & 3) << 4;      // 0,16,32,48 staging col start
    const int qi0 = (t >> 4) << 2;     // 0..60  this thread's 4 queries
    const int kj0 = (t & 15) << 2;     // 0..60  this thread's 4 keys / 4 dims

    // Stage Q (transposed, pre-scaled by 1/sqrt(Dh)=0.125)
    {
        const float* src = qkv + ((size_t)(b * T_SEQ + qt * 64 + lr) * (3 * D_MODEL))
                               + h * D_HEAD + lc;
        #pragma unroll
        for (int j = 0; j < 16; ++j)
            Qt[lc + j][lr] = src[j] * 0.125f;
    }
    if (t < 64) { mS[t] = -1e30f; lS[t] = 0.f; }

    float O[4][4];
    #pragma unroll
    for (int a = 0; a < 4; ++a)
        #pragma unroll
        for (int d = 0; d < 4; ++d) O[a][d] = 0.f;

    for (int kt = 0; kt <= qt; ++kt) {
        // ---- stage K (transposed) + V ----
        {
            const float* ks = qkv + ((size_t)(b * T_SEQ + kt * 64 + lr) * (3 * D_MODEL))
                                  + D_MODEL + h * D_HEAD + lc;
            const float* vs = ks + D_MODEL;
            #pragma unroll
            for (int j = 0; j < 16; ++j) {
                Kt[lc + j][lr] = ks[j];
                Vs[lr][lc + j] = vs[j];
            }
        }
        __syncthreads();

        // ---- scores: 4 queries x 4 keys per thread ----
        float s[4][4];
        #pragma unroll
        for (int a = 0; a < 4; ++a)
            #pragma unroll
            for (int c = 0; c < 4; ++c) s[a][c] = 0.f;

        #pragma unroll 4
        for (int d = 0; d < D_HEAD; ++d) {
            floatx4 qv = *(const floatx4*)&Qt[d][qi0];
            floatx4 kv = *(const floatx4*)&Kt[d][kj0];
            #pragma unroll
            for (int a = 0; a < 4; ++a)
                #pragma unroll
                for (int c = 0; c < 4; ++c) s[a][c] += qv[a] * kv[c];
        }
        if (kt == qt) {   // causal mask only matters on the diagonal tile
            #pragma unroll
            for (int a = 0; a < 4; ++a)
                #pragma unroll
                for (int c = 0; c < 4; ++c)
                    if (kj0 + c > qi0 + a) s[a][c] = -1e30f;
        }
        #pragma unroll
        for (int c = 0; c < 4; ++c) {
            floatx4 v = { s[0][c], s[1][c], s[2][c], s[3][c] };
            *(floatx4*)&Sc[kj0 + c][qi0] = v;
        }
        __syncthreads();

        // ---- online softmax (one thread per query row) ----
        if (t < 64) {
            const int qi = t;
            float mold = mS[qi];
            float mx = mold;
            for (int kj = 0; kj < 64; ++kj) mx = fmaxf(mx, Sc[kj][qi]);
            float alpha = __expf(mold - mx);   // first tile: exp(-huge)=0
            float sum = 0.f;
            for (int kj = 0; kj < 64; ++kj) {
                float p = __expf(Sc[kj][qi] - mx);   // masked -> 0
                Sc[kj][qi] = p;
                sum += p;
            }
            lS[qi] = lS[qi] * alpha + sum;
            aS[qi] = alpha;
            mS[qi] = mx;
        }
        __syncthreads();

        // ---- O update: 4 queries x 4 dims per thread ----
        #pragma unroll
        for (int a = 0; a < 4; ++a) {
            const float al = aS[qi0 + a];
            #pragma unroll
            for (int d = 0; d < 4; ++d) O[a][d] *= al;
        }
        #pragma unroll 4
        for (int kj = 0; kj < 64; ++kj) {
            floatx4 p = *(const floatx4*)&Sc[kj][qi0];
            floatx4 v = *(const floatx4*)&Vs[kj][kj0];
            #pragma unroll
            for (int a = 0; a < 4; ++a)
                #pragma unroll
                for (int d = 0; d < 4; ++d) O[a][d] += p[a] * v[d];
        }
        __syncthreads();   // protect Sc/Vs before next tile's staging
    }

    // ---- finalize + write y[b, q, h*64 + d] as bf16 ----
    #pragma unroll
    for (int a = 0; a < 4; ++a) {
        const float inv = 1.f / lS[qi0 + a];
        u16* dst = y + ((size_t)(b * T_SEQ + qt * 64 + qi0 + a) * D_MODEL)
                     + h * D_HEAD + kj0;
        #pragma unroll
        for (int d = 0; d < 4; ++d) dst[d] = f2b(O[a][d] * inv);
    }
}

// ---------------------------------------------------------------------------
extern "C" void kernel_launch(void* const* d_in, const int* in_sizes, int n_in,
                              void* d_out, int out_size, void* d_ws, size_t ws_size,
                              hipStream_t stream) {
    const float* x    = (const float*)d_in[0];   // [4096, 1024] fp32
    const float* Wqkv = (const float*)d_in[1];   // [3072, 1024] fp32
    const float* Wout = (const float*)d_in[2];   // [1024, 1024] fp32
    float* out = (float*)d_out;                  // [4096, 1024] fp32

    // Workspace layout (72 MB total):
    //   xb    bf16  8 MB @ 0
    //   Wqkvb bf16  6 MB @ 8 MB
    //   Woutb bf16  2 MB @ 14 MB
    //   qkv   fp32 48 MB @ 16 MB
    //   y     bf16  8 MB @ 64 MB
    u16*  xb    = (u16*)d_ws;
    u16*  wqkvb = xb + (size_t)BT * D_MODEL;                       // 4,194,304 elems
    u16*  woutb = wqkvb + (size_t)3 * D_MODEL * D_MODEL;           // +3,145,728
    float* qkv  = (float*)((char*)d_ws + (16u << 20));
    u16*  yb    = (u16*)((char*)d_ws + (64u << 20));

    // 0) fp32 -> bf16 conversions
    {
        const int n4x = (BT * D_MODEL) / 4;                 // 1,048,576
        const int n4q = (3 * D_MODEL * D_MODEL) / 4;        //   786,432
        const int n4o = (D_MODEL * D_MODEL) / 4;            //   262,144
        cvt_kernel<<<n4x / 256, 256, 0, stream>>>(x, xb, n4x);
        cvt_kernel<<<n4q / 256, 256, 0, stream>>>(Wqkv, wqkvb, n4q);
        cvt_kernel<<<n4o / 256, 256, 0, stream>>>(Wout, woutb, n4o);
    }

    // 1) QKV projection: [4096,1024] x [3072,1024]^T -> fp32 qkv [4096,3072]
    {
        const int waves = (BT / 16) * ((3 * D_MODEL) / 64);  // 12288
        gemm_nt_kernel<<<waves / 4, 256, 0, stream>>>(
            xb, wqkvb, qkv, BT, 3 * D_MODEL, D_MODEL);
    }

    // 2) Causal attention -> y bf16 [4096,1024]
    attn_kernel<<<B_SZ * N_HEADS * (T_SEQ / 64), 256, 0, stream>>>(qkv, yb);

    // 3) Output projection: [4096,1024] x [1024,1024]^T -> fp32 out
    {
        const int waves = (BT / 16) * (D_MODEL / 64);        // 4096
        gemm_nt_kernel<<<waves / 4, 256, 0, stream>>>(
            yb, woutb, out, BT, D_MODEL, D_MODEL);
    }
}

// Round 3
// 448.050 us; speedup vs baseline: 2.0419x; 2.0419x over previous
//
#include <hip/hip_runtime.h>
#include <hip/hip_bf16.h>

// Problem constants (B=2, T=2048, D=1024, H=16, Dh=64)
#define B_SZ    2
#define T_SEQ   2048
#define D_MODEL 1024
#define N_HEADS 16
#define D_HEAD  64
#define BT      (B_SZ * T_SEQ)   // 4096 rows

typedef unsigned short u16;
typedef __attribute__((ext_vector_type(8))) short  short8;    // 8 bf16 (4 VGPRs)
typedef __attribute__((ext_vector_type(4))) float  floatx4;   // MFMA acc
typedef __attribute__((ext_vector_type(4))) unsigned short ushortx4;

__device__ inline u16 f2b(float f) {
    __hip_bfloat16 h = __float2bfloat16(f);   // RNE
    return *(u16*)&h;
}

// ---------------------------------------------------------------------------
// fp32 -> bf16 conversion, 4 elems/thread
// ---------------------------------------------------------------------------
__global__ __launch_bounds__(256) void cvt_kernel(
    const float* __restrict__ in, u16* __restrict__ out, int n4)
{
    const int i = blockIdx.x * 256 + threadIdx.x;
    if (i >= n4) return;
    floatx4 v = ((const floatx4*)in)[i];
    ushortx4 r;
    r[0] = f2b(v[0]); r[1] = f2b(v[1]); r[2] = f2b(v[2]); r[3] = f2b(v[3]);
    ((ushortx4*)out)[i] = r;
}

// ---------------------------------------------------------------------------
// QKV projection GEMM (NT): qkv[t,e] = sum_k x[t,k] Wqkv[e,k].
// One wave = 16(m=t) x 64(n=e). Epilogue scatters into attention-native
// bf16 buffers: Qb[b,h,t,d] (prescaled 1/8), Kb[b,h,t,d], Vt[b,h,d,t].
// Each wave's 64-wide n-tile lies in exactly one of Q/K/V and one head.
// ---------------------------------------------------------------------------
__global__ __launch_bounds__(256) void gemm_qkv_kernel(
    const u16* __restrict__ A, const u16* __restrict__ B,
    u16* __restrict__ Qb, u16* __restrict__ Kb, u16* __restrict__ Vt)
{
    const int K      = D_MODEL;
    const int gw     = (blockIdx.x * 256 + threadIdx.x) >> 6;
    const int lane   = threadIdx.x & 63;
    const int tilesM = BT >> 4;          // 256
    const int row    = lane & 15;
    const int quad   = lane >> 4;
    const int tm     = gw % tilesM;
    const int tn     = gw / tilesM;      // 0..47

    const u16* Ap = A + (size_t)(tm * 16 + row) * K + quad * 8;
    const u16* Bp = B + (size_t)(tn * 64 + row) * K + quad * 8;

    floatx4 acc0 = {0.f, 0.f, 0.f, 0.f};
    floatx4 acc1 = acc0, acc2 = acc0, acc3 = acc0;

    for (int k = 0; k < K; k += 32) {
        short8 a  = *(const short8*)(Ap + k);
        short8 b0 = *(const short8*)(Bp + k);
        short8 b1 = *(const short8*)(Bp + 16 * K + k);
        short8 b2 = *(const short8*)(Bp + 32 * K + k);
        short8 b3 = *(const short8*)(Bp + 48 * K + k);
        acc0 = __builtin_amdgcn_mfma_f32_16x16x32_bf16(a, b0, acc0, 0, 0, 0);
        acc1 = __builtin_amdgcn_mfma_f32_16x16x32_bf16(a, b1, acc1, 0, 0, 0);
        acc2 = __builtin_amdgcn_mfma_f32_16x16x32_bf16(a, b2, acc2, 0, 0, 0);
        acc3 = __builtin_amdgcn_mfma_f32_16x16x32_bf16(a, b3, acc3, 0, 0, 0);
    }
    floatx4 acc[4] = {acc0, acc1, acc2, acc3};

    const int sec = tn >> 4;     // 0=Q, 1=K, 2=V  (wave-uniform)
    const int h   = tn & 15;

    #pragma unroll
    for (int i = 0; i < 4; ++i) {
        const int d = 16 * i + row;
        #pragma unroll
        for (int rr = 0; rr < 4; ++rr) {
            const int t  = tm * 16 + quad * 4 + rr;
            const int bb = t >> 11;
            const int tl = t & (T_SEQ - 1);
            const float v = acc[i][rr];
            if (sec == 0)
                Qb[((size_t)(bb * N_HEADS + h) * T_SEQ + tl) * D_HEAD + d] = f2b(v * 0.125f);
            else if (sec == 1)
                Kb[((size_t)(bb * N_HEADS + h) * T_SEQ + tl) * D_HEAD + d] = f2b(v);
            else
                Vt[((size_t)(bb * N_HEADS + h) * D_HEAD + d) * T_SEQ + tl] = f2b(v);
        }
    }
}

// ---------------------------------------------------------------------------
// Generic NT GEMM (fp32 out) for the output projection.
// ---------------------------------------------------------------------------
__global__ __launch_bounds__(256) void gemm_nt_kernel(
    const u16* __restrict__ A, const u16* __restrict__ B,
    float* __restrict__ C, int M, int N, int K)
{
    const int gw     = (blockIdx.x * 256 + threadIdx.x) >> 6;
    const int lane   = threadIdx.x & 63;
    const int tilesM = M >> 4;
    const int row    = lane & 15;
    const int quad   = lane >> 4;
    const int tm     = gw % tilesM;
    const int tn     = gw / tilesM;

    const u16* Ap = A + (size_t)(tm * 16 + row) * K + quad * 8;
    const u16* Bp = B + (size_t)(tn * 64 + row) * K + quad * 8;

    floatx4 acc0 = {0.f, 0.f, 0.f, 0.f};
    floatx4 acc1 = acc0, acc2 = acc0, acc3 = acc0;

    for (int k = 0; k < K; k += 32) {
        short8 a  = *(const short8*)(Ap + k);
        short8 b0 = *(const short8*)(Bp + k);
        short8 b1 = *(const short8*)(Bp + 16 * K + k);
        short8 b2 = *(const short8*)(Bp + 32 * K + k);
        short8 b3 = *(const short8*)(Bp + 48 * K + k);
        acc0 = __builtin_amdgcn_mfma_f32_16x16x32_bf16(a, b0, acc0, 0, 0, 0);
        acc1 = __builtin_amdgcn_mfma_f32_16x16x32_bf16(a, b1, acc1, 0, 0, 0);
        acc2 = __builtin_amdgcn_mfma_f32_16x16x32_bf16(a, b2, acc2, 0, 0, 0);
        acc3 = __builtin_amdgcn_mfma_f32_16x16x32_bf16(a, b3, acc3, 0, 0, 0);
    }

    #pragma unroll
    for (int rr = 0; rr < 4; ++rr) {
        const int m = tm * 16 + quad * 4 + rr;
        float* Cp = C + (size_t)m * N + tn * 64 + row;
        Cp[0]  = acc0[rr];
        Cp[16] = acc1[rr];
        Cp[32] = acc2[rr];
        Cp[48] = acc3[rr];
    }
}

// ---------------------------------------------------------------------------
// MFMA causal flash attention.
// Block = 4 waves = 64 queries (one (b,h,qt)); wave = 16 queries.
// Qb[b,h,t,d] bf16 prescaled; Kb[b,h,t,d] bf16; Vt[b,h,d,t] bf16.
// Per 64-key tile: stage K[64][64]/Vt[64][64] in LDS (stride 72),
// S = Q K^T via 8 MFMAs (C: key=lane&15, q=quad*4+reg), register online
// softmax (shfl_xor over the 16-lane col group), P -> per-wave LDS -> A-frag,
// O += P V via 8 MFMAs. Output y[t, h*64+d] bf16.
// ---------------------------------------------------------------------------
__global__ __launch_bounds__(256) void attn_mfma_kernel(
    const u16* __restrict__ Qb, const u16* __restrict__ Kb,
    const u16* __restrict__ Vt, u16* __restrict__ y)
{
    const int bid = blockIdx.x;
    const int qt  = bid >> 5;          // 0..31 (spread across co-resident blocks)
    const int h   = (bid >> 1) & 15;
    const int b   = bid & 1;
    const int bh  = b * N_HEADS + h;

    __shared__ __align__(16) u16 Ks[64][72];      // [key][d]
    __shared__ __align__(16) u16 Vs[64][72];      // [d][key]
    __shared__ __align__(16) u16 Pl[4][16][72];   // per-wave P [q][key]

    const int tid  = threadIdx.x;
    const int w    = tid >> 6;
    const int lane = tid & 63;
    const int col  = lane & 15;
    const int quad = lane >> 4;

    const int srow = tid >> 2;           // staging row 0..63
    const int sseg = (tid & 3) << 4;     // staging col 0,16,32,48

    // Q fragment (A-layout: m=col, k=quad*8+j), two 32-k chunks
    short8 qf0, qf1;
    {
        const u16* qp = Qb + ((size_t)(bh * T_SEQ + qt * 64 + w * 16 + col)) * D_HEAD + quad * 8;
        qf0 = *(const short8*)qp;
        qf1 = *(const short8*)(qp + 32);
    }

    float m_r[4] = {-INFINITY, -INFINITY, -INFINITY, -INFINITY};
    float l_r[4] = {0.f, 0.f, 0.f, 0.f};
    floatx4 O[4];
    #pragma unroll
    for (int dt = 0; dt < 4; ++dt) O[dt] = (floatx4){0.f, 0.f, 0.f, 0.f};

    const u16* kbase = Kb + (size_t)bh * T_SEQ * D_HEAD;
    const u16* vbase = Vt + (size_t)bh * D_HEAD * T_SEQ;

    for (int kt = 0; kt <= qt; ++kt) {
        // ---- stage K tile and V^T tile ----
        {
            const u16* ks = kbase + (size_t)(kt * 64 + srow) * D_HEAD + sseg;
            *(short8*)&Ks[srow][sseg]     = *(const short8*)ks;
            *(short8*)&Ks[srow][sseg + 8] = *(const short8*)(ks + 8);
            const u16* vs = vbase + (size_t)srow * T_SEQ + kt * 64 + sseg;
            *(short8*)&Vs[srow][sseg]     = *(const short8*)vs;
            *(short8*)&Vs[srow][sseg + 8] = *(const short8*)(vs + 8);
        }
        __syncthreads();

        const bool diag  = (kt == qt);
        const int  ctmax = diag ? w : 3;

        // ---- S = Q K^T (scaled Q), C-layout: key=col, q=quad*4+reg ----
        floatx4 S[4];
        #pragma unroll
        for (int ct = 0; ct < 4; ++ct) {
            if (ct <= ctmax) {
                const u16* kp = &Ks[ct * 16 + col][quad * 8];
                short8 b0 = *(const short8*)kp;
                short8 b1 = *(const short8*)(kp + 32);
                floatx4 acc = {0.f, 0.f, 0.f, 0.f};
                acc = __builtin_amdgcn_mfma_f32_16x16x32_bf16(qf0, b0, acc, 0, 0, 0);
                acc = __builtin_amdgcn_mfma_f32_16x16x32_bf16(qf1, b1, acc, 0, 0, 0);
                if (diag && ct == ctmax) {   // partial causal mask on the wave's own 16x16
                    #pragma unroll
                    for (int r = 0; r < 4; ++r)
                        if (col > quad * 4 + r) acc[r] = -1e30f;
                }
                S[ct] = acc;
            } else {
                S[ct] = (floatx4){-1e30f, -1e30f, -1e30f, -1e30f};
            }
        }

        // ---- online softmax (per query row = quad*4+r) ----
        float a_r[4];
        #pragma unroll
        for (int r = 0; r < 4; ++r) {
            float mx = fmaxf(fmaxf(S[0][r], S[1][r]), fmaxf(S[2][r], S[3][r]));
            #pragma unroll
            for (int off = 1; off < 16; off <<= 1)
                mx = fmaxf(mx, __shfl_xor(mx, off));
            const float mnew  = fmaxf(m_r[r], mx);
            a_r[r] = __expf(m_r[r] - mnew);       // first tile: exp(-inf)=0
            m_r[r] = mnew;
            float rs = 0.f;
            #pragma unroll
            for (int ct = 0; ct < 4; ++ct) {
                float p = __expf(S[ct][r] - mnew);   // masked/skipped -> 0
                S[ct][r] = p;
                rs += p;
            }
            #pragma unroll
            for (int off = 1; off < 16; off <<= 1)
                rs += __shfl_xor(rs, off);
            l_r[r] = l_r[r] * a_r[r] + rs;
        }
        #pragma unroll
        for (int dt = 0; dt < 4; ++dt)
            #pragma unroll
            for (int r = 0; r < 4; ++r) O[dt][r] *= a_r[r];

        // ---- P (C-layout) -> LDS -> A-layout fragments ----
        #pragma unroll
        for (int ct = 0; ct < 4; ++ct)
            #pragma unroll
            for (int r = 0; r < 4; ++r)
                Pl[w][quad * 4 + r][ct * 16 + col] = f2b(S[ct][r]);

        const int kchunks = diag ? ((ctmax * 16 + 15) >> 5) : 1;
        #pragma unroll
        for (int c = 0; c < 2; ++c) {
            if (c <= kchunks) {
                short8 pa = *(const short8*)&Pl[w][col][c * 32 + quad * 8];
                #pragma unroll
                for (int dt = 0; dt < 4; ++dt) {
                    short8 vb = *(const short8*)&Vs[dt * 16 + col][c * 32 + quad * 8];
                    O[dt] = __builtin_amdgcn_mfma_f32_16x16x32_bf16(pa, vb, O[dt], 0, 0, 0);
                }
            }
        }
        __syncthreads();   // protect Ks/Vs before next staging
    }

    // ---- finalize: y[b*T + q][h*64 + d] ----
    float inv[4];
    #pragma unroll
    for (int r = 0; r < 4; ++r) inv[r] = 1.0f / l_r[r];
    #pragma unroll
    for (int dt = 0; dt < 4; ++dt) {
        #pragma unroll
        for (int r = 0; r < 4; ++r) {
            const size_t q_g = (size_t)(b * T_SEQ + qt * 64 + w * 16 + quad * 4 + r);
            y[q_g * D_MODEL + h * D_HEAD + dt * 16 + col] = f2b(O[dt][r] * inv[r]);
        }
    }
}

// ---------------------------------------------------------------------------
extern "C" void kernel_launch(void* const* d_in, const int* in_sizes, int n_in,
                              void* d_out, int out_size, void* d_ws, size_t ws_size,
                              hipStream_t stream) {
    const float* x    = (const float*)d_in[0];   // [4096, 1024] fp32
    const float* Wqkv = (const float*)d_in[1];   // [3072, 1024] fp32
    const float* Wout = (const float*)d_in[2];   // [1024, 1024] fp32
    float* out = (float*)d_out;                  // [4096, 1024] fp32

    // Workspace layout (48 MB total):
    //   xb    bf16  8 MB @  0
    //   Wqkvb bf16  6 MB @  8 MB
    //   Woutb bf16  2 MB @ 14 MB
    //   Qb    bf16  8 MB @ 16 MB   [b,h,t,d] prescaled 1/8
    //   Kb    bf16  8 MB @ 24 MB   [b,h,t,d]
    //   Vt    bf16  8 MB @ 32 MB   [b,h,d,t]
    //   yb    bf16  8 MB @ 40 MB   [t, h*64+d]
    u16* xb    = (u16*)d_ws;
    u16* wqkvb = (u16*)((char*)d_ws + ( 8u << 20));
    u16* woutb = (u16*)((char*)d_ws + (14u << 20));
    u16* Qb    = (u16*)((char*)d_ws + (16u << 20));
    u16* Kb    = (u16*)((char*)d_ws + (24u << 20));
    u16* Vtb   = (u16*)((char*)d_ws + (32u << 20));
    u16* yb    = (u16*)((char*)d_ws + (40u << 20));

    // 0) fp32 -> bf16 conversions
    {
        const int n4x = (BT * D_MODEL) / 4;
        const int n4q = (3 * D_MODEL * D_MODEL) / 4;
        const int n4o = (D_MODEL * D_MODEL) / 4;
        cvt_kernel<<<n4x / 256, 256, 0, stream>>>(x, xb, n4x);
        cvt_kernel<<<n4q / 256, 256, 0, stream>>>(Wqkv, wqkvb, n4q);
        cvt_kernel<<<n4o / 256, 256, 0, stream>>>(Wout, woutb, n4o);
    }

    // 1) QKV projection -> Qb/Kb/Vt (bf16, attention-native layouts)
    {
        const int waves = (BT / 16) * ((3 * D_MODEL) / 64);  // 12288
        gemm_qkv_kernel<<<waves / 4, 256, 0, stream>>>(xb, wqkvb, Qb, Kb, Vtb);
    }

    // 2) MFMA causal flash attention -> yb
    attn_mfma_kernel<<<B_SZ * N_HEADS * (T_SEQ / 64), 256, 0, stream>>>(Qb, Kb, Vtb, yb);

    // 3) Output projection -> fp32 out
    {
        const int waves = (BT / 16) * (D_MODEL / 64);        // 4096
        gemm_nt_kernel<<<waves / 4, 256, 0, stream>>>(
            yb, woutb, out, BT, D_MODEL, D_MODEL);
    }
}

// Round 4
// 228.180 us; speedup vs baseline: 4.0095x; 1.9636x over previous
//
#include <hip/hip_runtime.h>
#include <hip/hip_bf16.h>

// Problem constants (B=2, T=2048, D=1024, H=16, Dh=64)
#define B_SZ    2
#define T_SEQ   2048
#define D_MODEL 1024
#define N_HEADS 16
#define D_HEAD  64
#define BT      (B_SZ * T_SEQ)   // 4096 rows

typedef unsigned short u16;
typedef __attribute__((ext_vector_type(8))) short  short8;    // 8 bf16 (4 VGPRs)
typedef __attribute__((ext_vector_type(4))) float  floatx4;   // MFMA acc
typedef __attribute__((ext_vector_type(4))) unsigned short ushortx4;

__device__ inline u16 f2b(float f) {
    __hip_bfloat16 h = __float2bfloat16(f);   // RNE
    return *(u16*)&h;
}

// async global->LDS, 16B per lane; LDS dest = wave-uniform base + lane*16
__device__ inline void gld_lds16(const void* g, void* l) {
    __builtin_amdgcn_global_load_lds(
        (const __attribute__((address_space(1))) void*)g,
        (__attribute__((address_space(3))) void*)l, 16, 0, 0);
}

// ---------------------------------------------------------------------------
// fp32 -> bf16 conversion, 4 elems/thread
// ---------------------------------------------------------------------------
__global__ __launch_bounds__(256) void cvt_kernel(
    const float* __restrict__ in, u16* __restrict__ out, int n4)
{
    const int i = blockIdx.x * 256 + threadIdx.x;
    if (i >= n4) return;
    floatx4 v = ((const floatx4*)in)[i];
    ushortx4 r;
    r[0] = f2b(v[0]); r[1] = f2b(v[1]); r[2] = f2b(v[2]); r[3] = f2b(v[3]);
    ((ushortx4*)out)[i] = r;
}

// ---------------------------------------------------------------------------
// m97-style tiled NT GEMM: C[m,n] = sum_k A[m,k] * B[n,k].
// Block = 256 threads = 4 waves; 128x128 tile; BK=32; LDS staged via
// global_load_lds width=16; wave = 64x64 = 4x4 MFMA 16x16x32 accumulators.
// M fixed at 4096 (tilesM=32): tm = bid&31, tn = bid>>5.
// EPI 0: qkv scatter epilogue -> Qb[b,h,t,d]*0.125, Kb[b,h,t,d], Vt[b,h,d,t]
// EPI 1: fp32 C write (output projection)
// ---------------------------------------------------------------------------
template <int EPI>
__global__ __launch_bounds__(256) void gemm_tile_kernel(
    const u16* __restrict__ A, const u16* __restrict__ B, int N, int K,
    float* __restrict__ C, u16* __restrict__ Qb, u16* __restrict__ Kb,
    u16* __restrict__ Vt)
{
    __shared__ __align__(16) u16 Ab[128][32];   // 8 KB, unpadded (gld_lds layout)
    __shared__ __align__(16) u16 Bb[128][32];   // 8 KB

    const int tid  = threadIdx.x;
    const int w    = tid >> 6;
    const int lane = tid & 63;
    const int col  = lane & 15;
    const int quad = lane >> 4;
    const int wm   = w & 1;          // wave row (0..1)
    const int wn   = w >> 1;         // wave col (0..1)

    const int tm = blockIdx.x & 31;
    const int tn = blockIdx.x >> 5;

    // Staging: wave w covers rows [w*32, w*32+32) of both tiles, 2 issues each.
    // lane l -> row_local = l>>2, k-seg = (l&3)*8  (matches LDS dest lane*16B).
    const int r0 = w * 32;
    const int lr = lane >> 2;
    const int ls = (lane & 3) << 3;
    const u16* gA0 = A + (size_t)(tm * 128 + r0 + lr) * K + ls;
    const u16* gA1 = gA0 + (size_t)16 * K;
    const u16* gB0 = B + (size_t)(tn * 128 + r0 + lr) * K + ls;
    const u16* gB1 = gB0 + (size_t)16 * K;
    u16* lA0 = &Ab[r0][0];
    u16* lA1 = &Ab[r0 + 16][0];
    u16* lB0 = &Bb[r0][0];
    u16* lB1 = &Bb[r0 + 16][0];

    floatx4 acc[4][4];
    #pragma unroll
    for (int i = 0; i < 4; ++i)
        #pragma unroll
        for (int j = 0; j < 4; ++j) acc[i][j] = (floatx4){0.f, 0.f, 0.f, 0.f};

    for (int k0 = 0; k0 < K; k0 += 32) {
        __syncthreads();   // previous iteration's readers done
        gld_lds16(gA0 + k0, lA0);
        gld_lds16(gA1 + k0, lA1);
        gld_lds16(gB0 + k0, lB0);
        gld_lds16(gB1 + k0, lB1);
        __syncthreads();   // staging visible

        short8 af[4], bf[4];
        #pragma unroll
        for (int mt = 0; mt < 4; ++mt)
            af[mt] = *(const short8*)&Ab[wm * 64 + mt * 16 + col][quad * 8];
        #pragma unroll
        for (int nt = 0; nt < 4; ++nt)
            bf[nt] = *(const short8*)&Bb[wn * 64 + nt * 16 + col][quad * 8];
        #pragma unroll
        for (int mt = 0; mt < 4; ++mt)
            #pragma unroll
            for (int nt = 0; nt < 4; ++nt)
                acc[mt][nt] = __builtin_amdgcn_mfma_f32_16x16x32_bf16(
                    af[mt], bf[nt], acc[mt][nt], 0, 0, 0);
    }

    // Epilogue. C/D layout: n = col, m = quad*4 + rr.
    #pragma unroll
    for (int nt = 0; nt < 4; ++nt) {
        const int gcol = tn * 128 + wn * 64 + nt * 16 + col;
        #pragma unroll
        for (int mt = 0; mt < 4; ++mt) {
            #pragma unroll
            for (int rr = 0; rr < 4; ++rr) {
                const int m = tm * 128 + wm * 64 + mt * 16 + quad * 4 + rr;
                const float v = acc[mt][nt][rr];
                if (EPI == 1) {
                    C[(size_t)m * N + gcol] = v;
                } else {
                    const int sec = gcol >> 10;          // 0=Q,1=K,2=V (wave-uniform)
                    const int h   = (gcol >> 6) & 15;    // wave-uniform
                    const int d   = gcol & 63;
                    const int bb  = m >> 11;
                    const int tl  = m & (T_SEQ - 1);
                    if (sec == 0)
                        Qb[((size_t)(bb * N_HEADS + h) * T_SEQ + tl) * D_HEAD + d] = f2b(v * 0.125f);
                    else if (sec == 1)
                        Kb[((size_t)(bb * N_HEADS + h) * T_SEQ + tl) * D_HEAD + d] = f2b(v);
                    else
                        Vt[((size_t)(bb * N_HEADS + h) * D_HEAD + d) * T_SEQ + tl] = f2b(v);
                }
            }
        }
    }
}

// ---------------------------------------------------------------------------
// MFMA causal flash attention (unchanged from round 3).
// Block = 4 waves = 64 queries (one (b,h,qt)); wave = 16 queries.
// ---------------------------------------------------------------------------
__global__ __launch_bounds__(256) void attn_mfma_kernel(
    const u16* __restrict__ Qb, const u16* __restrict__ Kb,
    const u16* __restrict__ Vt, u16* __restrict__ y)
{
    const int bid = blockIdx.x;
    const int qt  = bid >> 5;          // 0..31
    const int h   = (bid >> 1) & 15;
    const int b   = bid & 1;
    const int bh  = b * N_HEADS + h;

    __shared__ __align__(16) u16 Ks[64][72];      // [key][d]
    __shared__ __align__(16) u16 Vs[64][72];      // [d][key]
    __shared__ __align__(16) u16 Pl[4][16][72];   // per-wave P [q][key]

    const int tid  = threadIdx.x;
    const int w    = tid >> 6;
    const int lane = tid & 63;
    const int col  = lane & 15;
    const int quad = lane >> 4;

    const int srow = tid >> 2;
    const int sseg = (tid & 3) << 4;

    short8 qf0, qf1;
    {
        const u16* qp = Qb + ((size_t)(bh * T_SEQ + qt * 64 + w * 16 + col)) * D_HEAD + quad * 8;
        qf0 = *(const short8*)qp;
        qf1 = *(const short8*)(qp + 32);
    }

    float m_r[4] = {-INFINITY, -INFINITY, -INFINITY, -INFINITY};
    float l_r[4] = {0.f, 0.f, 0.f, 0.f};
    floatx4 O[4];
    #pragma unroll
    for (int dt = 0; dt < 4; ++dt) O[dt] = (floatx4){0.f, 0.f, 0.f, 0.f};

    const u16* kbase = Kb + (size_t)bh * T_SEQ * D_HEAD;
    const u16* vbase = Vt + (size_t)bh * D_HEAD * T_SEQ;

    for (int kt = 0; kt <= qt; ++kt) {
        {
            const u16* ks = kbase + (size_t)(kt * 64 + srow) * D_HEAD + sseg;
            *(short8*)&Ks[srow][sseg]     = *(const short8*)ks;
            *(short8*)&Ks[srow][sseg + 8] = *(const short8*)(ks + 8);
            const u16* vs = vbase + (size_t)srow * T_SEQ + kt * 64 + sseg;
            *(short8*)&Vs[srow][sseg]     = *(const short8*)vs;
            *(short8*)&Vs[srow][sseg + 8] = *(const short8*)(vs + 8);
        }
        __syncthreads();

        const bool diag  = (kt == qt);
        const int  ctmax = diag ? w : 3;

        floatx4 S[4];
        #pragma unroll
        for (int ct = 0; ct < 4; ++ct) {
            if (ct <= ctmax) {
                const u16* kp = &Ks[ct * 16 + col][quad * 8];
                short8 b0 = *(const short8*)kp;
                short8 b1 = *(const short8*)(kp + 32);
                floatx4 acc = {0.f, 0.f, 0.f, 0.f};
                acc = __builtin_amdgcn_mfma_f32_16x16x32_bf16(qf0, b0, acc, 0, 0, 0);
                acc = __builtin_amdgcn_mfma_f32_16x16x32_bf16(qf1, b1, acc, 0, 0, 0);
                if (diag && ct == ctmax) {
                    #pragma unroll
                    for (int r = 0; r < 4; ++r)
                        if (col > quad * 4 + r) acc[r] = -1e30f;
                }
                S[ct] = acc;
            } else {
                S[ct] = (floatx4){-1e30f, -1e30f, -1e30f, -1e30f};
            }
        }

        float a_r[4];
        #pragma unroll
        for (int r = 0; r < 4; ++r) {
            float mx = fmaxf(fmaxf(S[0][r], S[1][r]), fmaxf(S[2][r], S[3][r]));
            #pragma unroll
            for (int off = 1; off < 16; off <<= 1)
                mx = fmaxf(mx, __shfl_xor(mx, off));
            const float mnew  = fmaxf(m_r[r], mx);
            a_r[r] = __expf(m_r[r] - mnew);
            m_r[r] = mnew;
            float rs = 0.f;
            #pragma unroll
            for (int ct = 0; ct < 4; ++ct) {
                float p = __expf(S[ct][r] - mnew);
                S[ct][r] = p;
                rs += p;
            }
            #pragma unroll
            for (int off = 1; off < 16; off <<= 1)
                rs += __shfl_xor(rs, off);
            l_r[r] = l_r[r] * a_r[r] + rs;
        }
        #pragma unroll
        for (int dt = 0; dt < 4; ++dt)
            #pragma unroll
            for (int r = 0; r < 4; ++r) O[dt][r] *= a_r[r];

        #pragma unroll
        for (int ct = 0; ct < 4; ++ct)
            #pragma unroll
            for (int r = 0; r < 4; ++r)
                Pl[w][quad * 4 + r][ct * 16 + col] = f2b(S[ct][r]);

        const int kchunks = diag ? ((ctmax * 16 + 15) >> 5) : 1;
        #pragma unroll
        for (int c = 0; c < 2; ++c) {
            if (c <= kchunks) {
                short8 pa = *(const short8*)&Pl[w][col][c * 32 + quad * 8];
                #pragma unroll
                for (int dt = 0; dt < 4; ++dt) {
                    short8 vb = *(const short8*)&Vs[dt * 16 + col][c * 32 + quad * 8];
                    O[dt] = __builtin_amdgcn_mfma_f32_16x16x32_bf16(pa, vb, O[dt], 0, 0, 0);
                }
            }
        }
        __syncthreads();
    }

    float inv[4];
    #pragma unroll
    for (int r = 0; r < 4; ++r) inv[r] = 1.0f / l_r[r];
    #pragma unroll
    for (int dt = 0; dt < 4; ++dt) {
        #pragma unroll
        for (int r = 0; r < 4; ++r) {
            const size_t q_g = (size_t)(b * T_SEQ + qt * 64 + w * 16 + quad * 4 + r);
            y[q_g * D_MODEL + h * D_HEAD + dt * 16 + col] = f2b(O[dt][r] * inv[r]);
        }
    }
}

// ---------------------------------------------------------------------------
extern "C" void kernel_launch(void* const* d_in, const int* in_sizes, int n_in,
                              void* d_out, int out_size, void* d_ws, size_t ws_size,
                              hipStream_t stream) {
    const float* x    = (const float*)d_in[0];   // [4096, 1024] fp32
    const float* Wqkv = (const float*)d_in[1];   // [3072, 1024] fp32
    const float* Wout = (const float*)d_in[2];   // [1024, 1024] fp32
    float* out = (float*)d_out;                  // [4096, 1024] fp32

    // Workspace layout (48 MB total):
    //   xb    bf16  8 MB @  0
    //   Wqkvb bf16  6 MB @  8 MB
    //   Woutb bf16  2 MB @ 14 MB
    //   Qb    bf16  8 MB @ 16 MB   [b,h,t,d] prescaled 1/8
    //   Kb    bf16  8 MB @ 24 MB   [b,h,t,d]
    //   Vt    bf16  8 MB @ 32 MB   [b,h,d,t]
    //   yb    bf16  8 MB @ 40 MB   [t, h*64+d]
    u16* xb    = (u16*)d_ws;
    u16* wqkvb = (u16*)((char*)d_ws + ( 8u << 20));
    u16* woutb = (u16*)((char*)d_ws + (14u << 20));
    u16* Qb    = (u16*)((char*)d_ws + (16u << 20));
    u16* Kb    = (u16*)((char*)d_ws + (24u << 20));
    u16* Vtb   = (u16*)((char*)d_ws + (32u << 20));
    u16* yb    = (u16*)((char*)d_ws + (40u << 20));

    // 0) fp32 -> bf16 conversions
    {
        const int n4x = (BT * D_MODEL) / 4;
        const int n4q = (3 * D_MODEL * D_MODEL) / 4;
        const int n4o = (D_MODEL * D_MODEL) / 4;
        cvt_kernel<<<n4x / 256, 256, 0, stream>>>(x, xb, n4x);
        cvt_kernel<<<n4q / 256, 256, 0, stream>>>(Wqkv, wqkvb, n4q);
        cvt_kernel<<<n4o / 256, 256, 0, stream>>>(Wout, woutb, n4o);
    }

    // 1) QKV projection (128x128 tiles): 32 x 24 = 768 blocks
    gemm_tile_kernel<0><<<32 * (3 * D_MODEL / 128), 256, 0, stream>>>(
        xb, wqkvb, 3 * D_MODEL, D_MODEL, nullptr, Qb, Kb, Vtb);

    // 2) MFMA causal flash attention -> yb
    attn_mfma_kernel<<<B_SZ * N_HEADS * (T_SEQ / 64), 256, 0, stream>>>(Qb, Kb, Vtb, yb);

    // 3) Output projection (128x128 tiles): 32 x 8 = 256 blocks -> fp32 out
    gemm_tile_kernel<1><<<32 * (D_MODEL / 128), 256, 0, stream>>>(
        yb, woutb, D_MODEL, D_MODEL, out, nullptr, nullptr, nullptr);
}

// Round 5
// 212.660 us; speedup vs baseline: 4.3021x; 1.0730x over previous
//
#include <hip/hip_runtime.h>
#include <hip/hip_bf16.h>

// Problem constants (B=2, T=2048, D=1024, H=16, Dh=64)
#define B_SZ    2
#define T_SEQ   2048
#define D_MODEL 1024
#define N_HEADS 16
#define D_HEAD  64
#define BT      (B_SZ * T_SEQ)   // 4096 rows

typedef unsigned short u16;
typedef __attribute__((ext_vector_type(8))) short  short8;    // 8 bf16 (4 VGPRs)
typedef __attribute__((ext_vector_type(4))) float  floatx4;   // MFMA acc
typedef __attribute__((ext_vector_type(4))) unsigned short ushortx4;

__device__ inline u16 f2b(float f) {
    __hip_bfloat16 h = __float2bfloat16(f);   // RNE
    return *(u16*)&h;
}

// async global->LDS, 16B per lane; LDS dest = wave-uniform base + lane*16
__device__ inline void gld_lds16(const void* g, void* l) {
    __builtin_amdgcn_global_load_lds(
        (const __attribute__((address_space(1))) void*)g,
        (__attribute__((address_space(3))) void*)l, 16, 0, 0);
}

// ---------------------------------------------------------------------------
// fp32 -> bf16 conversion, 4 elems/thread
// ---------------------------------------------------------------------------
__global__ __launch_bounds__(256) void cvt_kernel(
    const float* __restrict__ in, u16* __restrict__ out, int n4)
{
    const int i = blockIdx.x * 256 + threadIdx.x;
    if (i >= n4) return;
    floatx4 v = ((const floatx4*)in)[i];
    ushortx4 r;
    r[0] = f2b(v[0]); r[1] = f2b(v[1]); r[2] = f2b(v[2]); r[3] = f2b(v[3]);
    ((ushortx4*)out)[i] = r;
}

// ---------------------------------------------------------------------------
// m97-style tiled NT GEMM: C[m,n] = sum_k A[m,k] * B[n,k].
// Block = 256 threads = 4 waves; 128x128 tile; BK=32; LDS staged via
// global_load_lds width=16; wave = 64x64 = 4x4 MFMA 16x16x32 accumulators.
// M fixed at 4096 (tilesM=32): tm = bid&31, tn = bid>>5.
// EPI 0: qkv scatter epilogue -> Qb[b,h,t,d]*0.125, Kb[b,h,t,d], Vt[b,h,d,t]
// EPI 1: fp32 C write (output projection)
// ---------------------------------------------------------------------------
template <int EPI>
__global__ __launch_bounds__(256) void gemm_tile_kernel(
    const u16* __restrict__ A, const u16* __restrict__ B, int N, int K,
    float* __restrict__ C, u16* __restrict__ Qb, u16* __restrict__ Kb,
    u16* __restrict__ Vt)
{
    __shared__ __align__(16) u16 Ab[128][32];   // 8 KB, unpadded (gld_lds layout)
    __shared__ __align__(16) u16 Bb[128][32];   // 8 KB

    const int tid  = threadIdx.x;
    const int w    = tid >> 6;
    const int lane = tid & 63;
    const int col  = lane & 15;
    const int quad = lane >> 4;
    const int wm   = w & 1;          // wave row (0..1)
    const int wn   = w >> 1;         // wave col (0..1)

    const int tm = blockIdx.x & 31;
    const int tn = blockIdx.x >> 5;

    const int r0 = w * 32;
    const int lr = lane >> 2;
    const int ls = (lane & 3) << 3;
    const u16* gA0 = A + (size_t)(tm * 128 + r0 + lr) * K + ls;
    const u16* gA1 = gA0 + (size_t)16 * K;
    const u16* gB0 = B + (size_t)(tn * 128 + r0 + lr) * K + ls;
    const u16* gB1 = gB0 + (size_t)16 * K;
    u16* lA0 = &Ab[r0][0];
    u16* lA1 = &Ab[r0 + 16][0];
    u16* lB0 = &Bb[r0][0];
    u16* lB1 = &Bb[r0 + 16][0];

    floatx4 acc[4][4];
    #pragma unroll
    for (int i = 0; i < 4; ++i)
        #pragma unroll
        for (int j = 0; j < 4; ++j) acc[i][j] = (floatx4){0.f, 0.f, 0.f, 0.f};

    for (int k0 = 0; k0 < K; k0 += 32) {
        __syncthreads();   // previous iteration's readers done
        gld_lds16(gA0 + k0, lA0);
        gld_lds16(gA1 + k0, lA1);
        gld_lds16(gB0 + k0, lB0);
        gld_lds16(gB1 + k0, lB1);
        __syncthreads();   // staging visible

        short8 af[4], bf[4];
        #pragma unroll
        for (int mt = 0; mt < 4; ++mt)
            af[mt] = *(const short8*)&Ab[wm * 64 + mt * 16 + col][quad * 8];
        #pragma unroll
        for (int nt = 0; nt < 4; ++nt)
            bf[nt] = *(const short8*)&Bb[wn * 64 + nt * 16 + col][quad * 8];
        #pragma unroll
        for (int mt = 0; mt < 4; ++mt)
            #pragma unroll
            for (int nt = 0; nt < 4; ++nt)
                acc[mt][nt] = __builtin_amdgcn_mfma_f32_16x16x32_bf16(
                    af[mt], bf[nt], acc[mt][nt], 0, 0, 0);
    }

    // Epilogue. C/D layout: n = col, m = quad*4 + rr.
    #pragma unroll
    for (int nt = 0; nt < 4; ++nt) {
        const int gcol = tn * 128 + wn * 64 + nt * 16 + col;
        #pragma unroll
        for (int mt = 0; mt < 4; ++mt) {
            #pragma unroll
            for (int rr = 0; rr < 4; ++rr) {
                const int m = tm * 128 + wm * 64 + mt * 16 + quad * 4 + rr;
                const float v = acc[mt][nt][rr];
                if (EPI == 1) {
                    C[(size_t)m * N + gcol] = v;
                } else {
                    const int sec = gcol >> 10;          // 0=Q,1=K,2=V (wave-uniform)
                    const int h   = (gcol >> 6) & 15;    // wave-uniform
                    const int d   = gcol & 63;
                    const int bb  = m >> 11;
                    const int tl  = m & (T_SEQ - 1);
                    if (sec == 0)
                        Qb[((size_t)(bb * N_HEADS + h) * T_SEQ + tl) * D_HEAD + d] = f2b(v * 0.125f);
                    else if (sec == 1)
                        Kb[((size_t)(bb * N_HEADS + h) * T_SEQ + tl) * D_HEAD + d] = f2b(v);
                    else
                        Vt[((size_t)(bb * N_HEADS + h) * D_HEAD + d) * T_SEQ + tl] = f2b(v);
                }
            }
        }
    }
}

// ---------------------------------------------------------------------------
// MFMA causal flash attention v2:
//  - double-buffered async K/V staging (global_load_lds w=16), 1 barrier/iter
//  - XOR-swizzled unpadded [64][64] LDS tiles (phys_seg = seg ^ (row&7))
//  - heaviest query tiles dispatched first (qt descending in blockIdx)
// Block = 4 waves = 64 queries; wave = 16 queries.
// ---------------------------------------------------------------------------
__global__ __launch_bounds__(256) void attn_mfma_kernel(
    const u16* __restrict__ Qb, const u16* __restrict__ Kb,
    const u16* __restrict__ Vt, u16* __restrict__ y)
{
    const int bid = blockIdx.x;
    const int qt  = 31 - (bid >> 5);   // heaviest (most key tiles) first
    const int h   = (bid >> 1) & 15;
    const int b   = bid & 1;
    const int bh  = b * N_HEADS + h;

    __shared__ __align__(16) u16 KV[2][2][64][64];   // [buf][K/V][row][swizzled col] 32 KB
    __shared__ __align__(16) u16 Pl[4][16][72];      // per-wave P [q][key], 9 KB

    const int tid  = threadIdx.x;
    const int w    = tid >> 6;
    const int lane = tid & 63;
    const int col  = lane & 15;
    const int quad = lane >> 4;

    // ---- staging geometry (fixed per lane) ----
    const int srl  = lane >> 3;                   // row within 8-row group
    const int sseg = ((lane & 7) ^ srl) << 3;     // swizzled u16 col offset
    const int row0 = w * 16 + srl;
    const u16* kbase = Kb + (size_t)bh * T_SEQ * D_HEAD;
    const u16* vbase = Vt + (size_t)bh * D_HEAD * T_SEQ;
    const size_t offK0 = (size_t)row0 * D_HEAD + sseg;
    const size_t offK1 = offK0 + (size_t)8 * D_HEAD;
    const size_t offV0 = (size_t)row0 * T_SEQ + sseg;
    const size_t offV1 = offV0 + (size_t)8 * T_SEQ;

    // ---- Q fragment (A-layout: m=col, k=quad*8+j), two 32-k chunks ----
    short8 qf0, qf1;
    {
        const u16* qp = Qb + ((size_t)(bh * T_SEQ + qt * 64 + w * 16 + col)) * D_HEAD + quad * 8;
        qf0 = *(const short8*)qp;
        qf1 = *(const short8*)(qp + 32);
    }

    float m_r[4] = {-INFINITY, -INFINITY, -INFINITY, -INFINITY};
    float l_r[4] = {0.f, 0.f, 0.f, 0.f};
    floatx4 O[4];
    #pragma unroll
    for (int dt = 0; dt < 4; ++dt) O[dt] = (floatx4){0.f, 0.f, 0.f, 0.f};

    // frag-read swizzle constants
    const int c7 = col & 7;
    const int sA = (quad ^ c7) << 3;          // phys col, k-chunk 0
    const int sB = ((quad ^ c7) ^ 4) << 3;    // phys col, k-chunk 1

    // prefetch tile 0 into buffer 0
    {
        const u16* kt_k = kbase;
        const u16* kt_v = vbase;
        gld_lds16(kt_k + offK0, &KV[0][0][w * 16][0]);
        gld_lds16(kt_k + offK1, &KV[0][0][w * 16 + 8][0]);
        gld_lds16(kt_v + offV0, &KV[0][1][w * 16][0]);
        gld_lds16(kt_v + offV1, &KV[0][1][w * 16 + 8][0]);
    }

    for (int kt = 0; kt <= qt; ++kt) {
        __syncthreads();   // buf[kt&1] staged; buf[(kt+1)&1] readers (iter kt-1) done

        if (kt < qt) {     // prefetch next tile into the other buffer
            const int nb = (kt + 1) & 1;
            const u16* kt_k = kbase + (size_t)(kt + 1) * 64 * D_HEAD;
            const u16* kt_v = vbase + (size_t)(kt + 1) * 64;
            gld_lds16(kt_k + offK0, &KV[nb][0][w * 16][0]);
            gld_lds16(kt_k + offK1, &KV[nb][0][w * 16 + 8][0]);
            gld_lds16(kt_v + offV0, &KV[nb][1][w * 16][0]);
            gld_lds16(kt_v + offV1, &KV[nb][1][w * 16 + 8][0]);
        }

        const u16 (*Ksb)[64] = KV[kt & 1][0];
        const u16 (*Vsb)[64] = KV[kt & 1][1];

        const bool diag  = (kt == qt);
        const int  ctmax = diag ? w : 3;

        // ---- S = Q K^T, C-layout: key=col, q=quad*4+reg ----
        floatx4 S[4];
        #pragma unroll
        for (int ct = 0; ct < 4; ++ct) {
            if (ct <= ctmax) {
                const u16* kp = &Ksb[ct * 16 + col][0];
                short8 b0 = *(const short8*)(kp + sA);
                short8 b1 = *(const short8*)(kp + sB);
                floatx4 acc = {0.f, 0.f, 0.f, 0.f};
                acc = __builtin_amdgcn_mfma_f32_16x16x32_bf16(qf0, b0, acc, 0, 0, 0);
                acc = __builtin_amdgcn_mfma_f32_16x16x32_bf16(qf1, b1, acc, 0, 0, 0);
                if (diag && ct == ctmax) {   // causal mask on the wave's own 16x16
                    #pragma unroll
                    for (int r = 0; r < 4; ++r)
                        if (col > quad * 4 + r) acc[r] = -1e30f;
                }
                S[ct] = acc;
            } else {
                S[ct] = (floatx4){-1e30f, -1e30f, -1e30f, -1e30f};
            }
        }

        // ---- online softmax (per query row = quad*4+r) ----
        float a_r[4];
        #pragma unroll
        for (int r = 0; r < 4; ++r) {
            float mx = fmaxf(fmaxf(S[0][r], S[1][r]), fmaxf(S[2][r], S[3][r]));
            #pragma unroll
            for (int off = 1; off < 16; off <<= 1)
                mx = fmaxf(mx, __shfl_xor(mx, off));
            const float mnew  = fmaxf(m_r[r], mx);
            a_r[r] = __expf(m_r[r] - mnew);       // first tile: exp(-inf)=0
            m_r[r] = mnew;
            float rs = 0.f;
            #pragma unroll
            for (int ct = 0; ct < 4; ++ct) {
                float p = __expf(S[ct][r] - mnew);   // masked/skipped -> 0
                S[ct][r] = p;
                rs += p;
            }
            #pragma unroll
            for (int off = 1; off < 16; off <<= 1)
                rs += __shfl_xor(rs, off);
            l_r[r] = l_r[r] * a_r[r] + rs;
        }
        #pragma unroll
        for (int dt = 0; dt < 4; ++dt)
            #pragma unroll
            for (int r = 0; r < 4; ++r) O[dt][r] *= a_r[r];

        // ---- P (C-layout) -> per-wave LDS -> A-layout fragments ----
        #pragma unroll
        for (int ct = 0; ct < 4; ++ct)
            #pragma unroll
            for (int r = 0; r < 4; ++r)
                Pl[w][quad * 4 + r][ct * 16 + col] = f2b(S[ct][r]);

        const int kchunks = diag ? ((ctmax * 16 + 15) >> 5) : 1;
        #pragma unroll
        for (int c = 0; c < 2; ++c) {
            if (c <= kchunks) {
                short8 pa = *(const short8*)&Pl[w][col][c * 32 + quad * 8];
                #pragma unroll
                for (int dt = 0; dt < 4; ++dt) {
                    const u16* vp = &Vsb[dt * 16 + col][0];
                    short8 vb = *(const short8*)(vp + (c ? sB : sA));
                    O[dt] = __builtin_amdgcn_mfma_f32_16x16x32_bf16(pa, vb, O[dt], 0, 0, 0);
                }
            }
        }
    }

    // ---- finalize: y[b*T + q][h*64 + d] ----
    float inv[4];
    #pragma unroll
    for (int r = 0; r < 4; ++r) inv[r] = 1.0f / l_r[r];
    #pragma unroll
    for (int dt = 0; dt < 4; ++dt) {
        #pragma unroll
        for (int r = 0; r < 4; ++r) {
            const size_t q_g = (size_t)(b * T_SEQ + qt * 64 + w * 16 + quad * 4 + r);
            y[q_g * D_MODEL + h * D_HEAD + dt * 16 + col] = f2b(O[dt][r] * inv[r]);
        }
    }
}

// ---------------------------------------------------------------------------
extern "C" void kernel_launch(void* const* d_in, const int* in_sizes, int n_in,
                              void* d_out, int out_size, void* d_ws, size_t ws_size,
                              hipStream_t stream) {
    const float* x    = (const float*)d_in[0];   // [4096, 1024] fp32
    const float* Wqkv = (const float*)d_in[1];   // [3072, 1024] fp32
    const float* Wout = (const float*)d_in[2];   // [1024, 1024] fp32
    float* out = (float*)d_out;                  // [4096, 1024] fp32

    // Workspace layout (48 MB total):
    //   xb    bf16  8 MB @  0
    //   Wqkvb bf16  6 MB @  8 MB
    //   Woutb bf16  2 MB @ 14 MB
    //   Qb    bf16  8 MB @ 16 MB   [b,h,t,d] prescaled 1/8
    //   Kb    bf16  8 MB @ 24 MB   [b,h,t,d]
    //   Vt    bf16  8 MB @ 32 MB   [b,h,d,t]
    //   yb    bf16  8 MB @ 40 MB   [t, h*64+d]
    u16* xb    = (u16*)d_ws;
    u16* wqkvb = (u16*)((char*)d_ws + ( 8u << 20));
    u16* woutb = (u16*)((char*)d_ws + (14u << 20));
    u16* Qb    = (u16*)((char*)d_ws + (16u << 20));
    u16* Kb    = (u16*)((char*)d_ws + (24u << 20));
    u16* Vtb   = (u16*)((char*)d_ws + (32u << 20));
    u16* yb    = (u16*)((char*)d_ws + (40u << 20));

    // 0) fp32 -> bf16 conversions
    {
        const int n4x = (BT * D_MODEL) / 4;
        const int n4q = (3 * D_MODEL * D_MODEL) / 4;
        const int n4o = (D_MODEL * D_MODEL) / 4;
        cvt_kernel<<<n4x / 256, 256, 0, stream>>>(x, xb, n4x);
        cvt_kernel<<<n4q / 256, 256, 0, stream>>>(Wqkv, wqkvb, n4q);
        cvt_kernel<<<n4o / 256, 256, 0, stream>>>(Wout, woutb, n4o);
    }

    // 1) QKV projection (128x128 tiles): 32 x 24 = 768 blocks
    gemm_tile_kernel<0><<<32 * (3 * D_MODEL / 128), 256, 0, stream>>>(
        xb, wqkvb, 3 * D_MODEL, D_MODEL, nullptr, Qb, Kb, Vtb);

    // 2) MFMA causal flash attention -> yb
    attn_mfma_kernel<<<B_SZ * N_HEADS * (T_SEQ / 64), 256, 0, stream>>>(Qb, Kb, Vtb, yb);

    // 3) Output projection (128x128 tiles): 32 x 8 = 256 blocks -> fp32 out
    gemm_tile_kernel<1><<<32 * (D_MODEL / 128), 256, 0, stream>>>(
        yb, woutb, D_MODEL, D_MODEL, out, nullptr, nullptr, nullptr);
}

// Round 6
// 190.576 us; speedup vs baseline: 4.8006x; 1.1159x over previous
//
#include <hip/hip_runtime.h>
#include <hip/hip_bf16.h>

// Problem constants (B=2, T=2048, D=1024, H=16, Dh=64)
#define B_SZ    2
#define T_SEQ   2048
#define D_MODEL 1024
#define N_HEADS 16
#define D_HEAD  64
#define BT      (B_SZ * T_SEQ)   // 4096 rows

typedef unsigned short u16;
typedef __attribute__((ext_vector_type(8))) short  short8;    // 8 bf16 (4 VGPRs)
typedef __attribute__((ext_vector_type(4))) float  floatx4;   // MFMA acc
typedef __attribute__((ext_vector_type(4))) unsigned short ushortx4;

__device__ inline u16 f2b(float f) {
    __hip_bfloat16 h = __float2bfloat16(f);   // RNE
    return *(u16*)&h;
}

// async global->LDS, 16B per lane; LDS dest = wave-uniform base + lane*16
__device__ inline void gld_lds16(const void* g, void* l) {
    __builtin_amdgcn_global_load_lds(
        (const __attribute__((address_space(1))) void*)g,
        (__attribute__((address_space(3))) void*)l, 16, 0, 0);
}

// ---------------------------------------------------------------------------
// fp32 -> bf16 conversion for all three inputs in ONE dispatch.
// ---------------------------------------------------------------------------
__global__ __launch_bounds__(256) void cvt3_kernel(
    const float* __restrict__ x, const float* __restrict__ wq,
    const float* __restrict__ wo,
    u16* __restrict__ xb, u16* __restrict__ wqb, u16* __restrict__ wob)
{
    const int n4x = (BT * D_MODEL) / 4;
    const int n4q = (3 * D_MODEL * D_MODEL) / 4;
    const int n4o = (D_MODEL * D_MODEL) / 4;
    int i = blockIdx.x * 256 + threadIdx.x;
    const float* src; u16* dst;
    if (i < n4x)            { src = x;  dst = xb;  }
    else if (i < n4x + n4q) { i -= n4x; src = wq; dst = wqb; }
    else                    { i -= n4x + n4q; if (i >= n4o) return; src = wo; dst = wob; }
    floatx4 v = ((const floatx4*)src)[i];
    ushortx4 r;
    r[0] = f2b(v[0]); r[1] = f2b(v[1]); r[2] = f2b(v[2]); r[3] = f2b(v[3]);
    ((ushortx4*)dst)[i] = r;
}

// ---------------------------------------------------------------------------
// m97-style tiled NT GEMM: C[m,n] = sum_k A[m,k] * B[n,k].
// Block = 256 threads = 4 waves; 128x128 tile; BK=32; LDS staged via
// global_load_lds width=16; wave = 64x64 = 4x4 MFMA 16x16x32 accumulators.
// EPI 0: qkv scatter epilogue -> Qb[b,h,t,d]*0.125, Kb[b,h,t,d], Vt[b,h,d,t]
// EPI 1: fp32 C write (output projection)
// ---------------------------------------------------------------------------
template <int EPI>
__global__ __launch_bounds__(256) void gemm_tile_kernel(
    const u16* __restrict__ A, const u16* __restrict__ B, int N, int K,
    float* __restrict__ C, u16* __restrict__ Qb, u16* __restrict__ Kb,
    u16* __restrict__ Vt)
{
    __shared__ __align__(16) u16 Ab[128][32];   // 8 KB, unpadded (gld_lds layout)
    __shared__ __align__(16) u16 Bb[128][32];   // 8 KB

    const int tid  = threadIdx.x;
    const int w    = tid >> 6;
    const int lane = tid & 63;
    const int col  = lane & 15;
    const int quad = lane >> 4;
    const int wm   = w & 1;
    const int wn   = w >> 1;

    const int tm = blockIdx.x & 31;
    const int tn = blockIdx.x >> 5;

    const int r0 = w * 32;
    const int lr = lane >> 2;
    const int ls = (lane & 3) << 3;
    const u16* gA0 = A + (size_t)(tm * 128 + r0 + lr) * K + ls;
    const u16* gA1 = gA0 + (size_t)16 * K;
    const u16* gB0 = B + (size_t)(tn * 128 + r0 + lr) * K + ls;
    const u16* gB1 = gB0 + (size_t)16 * K;
    u16* lA0 = &Ab[r0][0];
    u16* lA1 = &Ab[r0 + 16][0];
    u16* lB0 = &Bb[r0][0];
    u16* lB1 = &Bb[r0 + 16][0];

    floatx4 acc[4][4];
    #pragma unroll
    for (int i = 0; i < 4; ++i)
        #pragma unroll
        for (int j = 0; j < 4; ++j) acc[i][j] = (floatx4){0.f, 0.f, 0.f, 0.f};

    for (int k0 = 0; k0 < K; k0 += 32) {
        __syncthreads();
        gld_lds16(gA0 + k0, lA0);
        gld_lds16(gA1 + k0, lA1);
        gld_lds16(gB0 + k0, lB0);
        gld_lds16(gB1 + k0, lB1);
        __syncthreads();

        short8 af[4], bf[4];
        #pragma unroll
        for (int mt = 0; mt < 4; ++mt)
            af[mt] = *(const short8*)&Ab[wm * 64 + mt * 16 + col][quad * 8];
        #pragma unroll
        for (int nt = 0; nt < 4; ++nt)
            bf[nt] = *(const short8*)&Bb[wn * 64 + nt * 16 + col][quad * 8];
        #pragma unroll
        for (int mt = 0; mt < 4; ++mt)
            #pragma unroll
            for (int nt = 0; nt < 4; ++nt)
                acc[mt][nt] = __builtin_amdgcn_mfma_f32_16x16x32_bf16(
                    af[mt], bf[nt], acc[mt][nt], 0, 0, 0);
    }

    // Epilogue. C/D layout: n = col, m = quad*4 + rr.
    #pragma unroll
    for (int nt = 0; nt < 4; ++nt) {
        const int gcol = tn * 128 + wn * 64 + nt * 16 + col;
        #pragma unroll
        for (int mt = 0; mt < 4; ++mt) {
            #pragma unroll
            for (int rr = 0; rr < 4; ++rr) {
                const int m = tm * 128 + wm * 64 + mt * 16 + quad * 4 + rr;
                const float v = acc[mt][nt][rr];
                if (EPI == 1) {
                    C[(size_t)m * N + gcol] = v;
                } else {
                    const int sec = gcol >> 10;          // 0=Q,1=K,2=V (wave-uniform)
                    const int h   = (gcol >> 6) & 15;    // wave-uniform
                    const int d   = gcol & 63;
                    const int bb  = m >> 11;
                    const int tl  = m & (T_SEQ - 1);
                    if (sec == 0)
                        Qb[((size_t)(bb * N_HEADS + h) * T_SEQ + tl) * D_HEAD + d] = f2b(v * 0.125f);
                    else if (sec == 1)
                        Kb[((size_t)(bb * N_HEADS + h) * T_SEQ + tl) * D_HEAD + d] = f2b(v);
                    else
                        Vt[((size_t)(bb * N_HEADS + h) * D_HEAD + d) * T_SEQ + tl] = f2b(v);
                }
            }
        }
    }
}

// ---------------------------------------------------------------------------
// MFMA causal flash attention v3 (S^T formulation):
//  - S^T = K Q^T  (operand-swapped MFMA; identical LDS addressing) so C-layout
//    col = query: each lane's 16 S values belong to ONE query -> softmax
//    reduction is in-register + 2 shuffle stages (was 4 rows x 8 stages).
//  - P pack: 4x ds_write_b64 (was 16x ds_write_b16).
//  - alpha / l redistribution to O's row-indexed layout via 4 __shfl.
//  - double-buffered async K/V staging, XOR-swizzled LDS, heaviest-qt first.
// Block = 4 waves = 64 queries; wave = 16 queries.
// ---------------------------------------------------------------------------
__global__ __launch_bounds__(256) void attn_mfma_kernel(
    const u16* __restrict__ Qb, const u16* __restrict__ Kb,
    const u16* __restrict__ Vt, u16* __restrict__ y)
{
    const int bid = blockIdx.x;
    const int qt  = 31 - (bid >> 5);   // heaviest (most key tiles) first
    const int h   = (bid >> 1) & 15;
    const int b   = bid & 1;
    const int bh  = b * N_HEADS + h;

    __shared__ __align__(16) u16 KV[2][2][64][64];   // [buf][K/V][row][swizzled col] 32 KB
    __shared__ __align__(16) u16 Pl[4][16][72];      // per-wave P [q][key], 9 KB

    const int tid  = threadIdx.x;
    const int w    = tid >> 6;
    const int lane = tid & 63;
    const int col  = lane & 15;
    const int quad = lane >> 4;

    // ---- staging geometry ----
    const int srl  = lane >> 3;
    const int sseg = ((lane & 7) ^ srl) << 3;
    const int row0 = w * 16 + srl;
    const u16* kbase = Kb + (size_t)bh * T_SEQ * D_HEAD;
    const u16* vbase = Vt + (size_t)bh * D_HEAD * T_SEQ;
    const size_t offK0 = (size_t)row0 * D_HEAD + sseg;
    const size_t offK1 = offK0 + (size_t)8 * D_HEAD;
    const size_t offV0 = (size_t)row0 * T_SEQ + sseg;
    const size_t offV1 = offV0 + (size_t)8 * T_SEQ;

    // ---- Q fragment (B-layout: n=col=query, k=quad*8+j), two 32-k chunks ----
    short8 qf0, qf1;
    {
        const u16* qp = Qb + ((size_t)(bh * T_SEQ + qt * 64 + w * 16 + col)) * D_HEAD + quad * 8;
        qf0 = *(const short8*)qp;
        qf1 = *(const short8*)(qp + 32);
    }

    // softmax state: per-lane scalar, query = w*16 + col (replicated across quads)
    float m_s = -INFINITY;
    float l_s = 0.f;
    floatx4 O[4];   // O[dt]: C-layout col=d, row(reg)=query quad*4+r
    #pragma unroll
    for (int dt = 0; dt < 4; ++dt) O[dt] = (floatx4){0.f, 0.f, 0.f, 0.f};

    // frag-read swizzle constants
    const int c7 = col & 7;
    const int sA = (quad ^ c7) << 3;          // phys col, k-chunk 0
    const int sB = ((quad ^ c7) ^ 4) << 3;    // phys col, k-chunk 1

    // prefetch tile 0 into buffer 0
    gld_lds16(kbase + offK0, &KV[0][0][w * 16][0]);
    gld_lds16(kbase + offK1, &KV[0][0][w * 16 + 8][0]);
    gld_lds16(vbase + offV0, &KV[0][1][w * 16][0]);
    gld_lds16(vbase + offV1, &KV[0][1][w * 16 + 8][0]);

    for (int kt = 0; kt <= qt; ++kt) {
        __syncthreads();   // buf[kt&1] staged; other buf's readers done

        if (kt < qt) {
            const int nb = (kt + 1) & 1;
            const u16* kt_k = kbase + (size_t)(kt + 1) * 64 * D_HEAD;
            const u16* kt_v = vbase + (size_t)(kt + 1) * 64;
            gld_lds16(kt_k + offK0, &KV[nb][0][w * 16][0]);
            gld_lds16(kt_k + offK1, &KV[nb][0][w * 16 + 8][0]);
            gld_lds16(kt_v + offV0, &KV[nb][1][w * 16][0]);
            gld_lds16(kt_v + offV1, &KV[nb][1][w * 16 + 8][0]);
        }

        const u16 (*Ksb)[64] = KV[kt & 1][0];
        const u16 (*Vsb)[64] = KV[kt & 1][1];

        const bool diag  = (kt == qt);
        const int  ctmax = diag ? w : 3;

        // ---- S^T = K Q^T. C-layout: col=query, row(reg)=key ct*16+quad*4+r ----
        floatx4 S[4];
        #pragma unroll
        for (int ct = 0; ct < 4; ++ct) {
            if (ct <= ctmax) {
                const u16* kp = &Ksb[ct * 16 + col][0];
                short8 k0 = *(const short8*)(kp + sA);
                short8 k1 = *(const short8*)(kp + sB);
                floatx4 acc = {0.f, 0.f, 0.f, 0.f};
                acc = __builtin_amdgcn_mfma_f32_16x16x32_bf16(k0, qf0, acc, 0, 0, 0);
                acc = __builtin_amdgcn_mfma_f32_16x16x32_bf16(k1, qf1, acc, 0, 0, 0);
                if (diag && ct == ctmax) {   // mask: key quad*4+r > query col
                    #pragma unroll
                    for (int r = 0; r < 4; ++r)
                        if (quad * 4 + r > col) acc[r] = -1e30f;
                }
                S[ct] = acc;
            } else {
                S[ct] = (floatx4){-1e30f, -1e30f, -1e30f, -1e30f};
            }
        }

        // ---- online softmax: all 16 values belong to query=col ----
        floatx4 mv;
        #pragma unroll
        for (int r = 0; r < 4; ++r)
            mv[r] = fmaxf(fmaxf(S[0][r], S[1][r]), fmaxf(S[2][r], S[3][r]));
        float mloc = fmaxf(fmaxf(mv[0], mv[1]), fmaxf(mv[2], mv[3]));
        mloc = fmaxf(mloc, __shfl_xor(mloc, 16));
        mloc = fmaxf(mloc, __shfl_xor(mloc, 32));
        const float mnew  = fmaxf(m_s, mloc);
        const float alpha = __expf(m_s - mnew);   // first tile: exp(-inf)=0
        m_s = mnew;

        float rs = 0.f;
        #pragma unroll
        for (int ct = 0; ct < 4; ++ct) {
            #pragma unroll
            for (int r = 0; r < 4; ++r) {
                float p = __expf(S[ct][r] - mnew);   // masked/skipped -> 0
                S[ct][r] = p;
                rs += p;
            }
        }
        rs += __shfl_xor(rs, 16);
        rs += __shfl_xor(rs, 32);
        l_s = l_s * alpha + rs;

        // ---- redistribute alpha to O's row-indexed layout; rescale O ----
        float a_row[4];
        #pragma unroll
        for (int r = 0; r < 4; ++r) a_row[r] = __shfl(alpha, quad * 4 + r);
        #pragma unroll
        for (int dt = 0; dt < 4; ++dt)
            #pragma unroll
            for (int r = 0; r < 4; ++r) O[dt][r] *= a_row[r];

        // ---- P^T (col=query, rows=4 contiguous keys) -> Pl[q][key], b64 ----
        #pragma unroll
        for (int ct = 0; ct < 4; ++ct) {
            ushortx4 pk;
            pk[0] = f2b(S[ct][0]); pk[1] = f2b(S[ct][1]);
            pk[2] = f2b(S[ct][2]); pk[3] = f2b(S[ct][3]);
            *(ushortx4*)&Pl[w][col][ct * 16 + quad * 4] = pk;
        }

        // ---- O += P V : A = P (m=query), B = V^T (n=d) ----
        const int kchunks = diag ? ((ctmax * 16 + 15) >> 5) : 1;
        #pragma unroll
        for (int c = 0; c < 2; ++c) {
            if (c <= kchunks) {
                short8 pa = *(const short8*)&Pl[w][col][c * 32 + quad * 8];
                #pragma unroll
                for (int dt = 0; dt < 4; ++dt) {
                    const u16* vp = &Vsb[dt * 16 + col][0];
                    short8 vb = *(const short8*)(vp + (c ? sB : sA));
                    O[dt] = __builtin_amdgcn_mfma_f32_16x16x32_bf16(pa, vb, O[dt], 0, 0, 0);
                }
            }
        }
    }

    // ---- finalize: inv(l) per O row, write y[b*T + q][h*64 + d] ----
    float inv_row[4];
    #pragma unroll
    for (int r = 0; r < 4; ++r) inv_row[r] = 1.0f / __shfl(l_s, quad * 4 + r);
    #pragma unroll
    for (int dt = 0; dt < 4; ++dt) {
        #pragma unroll
        for (int r = 0; r < 4; ++r) {
            const size_t q_g = (size_t)(b * T_SEQ + qt * 64 + w * 16 + quad * 4 + r);
            y[q_g * D_MODEL + h * D_HEAD + dt * 16 + col] = f2b(O[dt][r] * inv_row[r]);
        }
    }
}

// ---------------------------------------------------------------------------
extern "C" void kernel_launch(void* const* d_in, const int* in_sizes, int n_in,
                              void* d_out, int out_size, void* d_ws, size_t ws_size,
                              hipStream_t stream) {
    const float* x    = (const float*)d_in[0];   // [4096, 1024] fp32
    const float* Wqkv = (const float*)d_in[1];   // [3072, 1024] fp32
    const float* Wout = (const float*)d_in[2];   // [1024, 1024] fp32
    float* out = (float*)d_out;                  // [4096, 1024] fp32

    // Workspace layout (48 MB total):
    //   xb    bf16  8 MB @  0
    //   Wqkvb bf16  6 MB @  8 MB
    //   Woutb bf16  2 MB @ 14 MB
    //   Qb    bf16  8 MB @ 16 MB   [b,h,t,d] prescaled 1/8
    //   Kb    bf16  8 MB @ 24 MB   [b,h,t,d]
    //   Vt    bf16  8 MB @ 32 MB   [b,h,d,t]
    //   yb    bf16  8 MB @ 40 MB   [t, h*64+d]
    u16* xb    = (u16*)d_ws;
    u16* wqkvb = (u16*)((char*)d_ws + ( 8u << 20));
    u16* woutb = (u16*)((char*)d_ws + (14u << 20));
    u16* Qb    = (u16*)((char*)d_ws + (16u << 20));
    u16* Kb    = (u16*)((char*)d_ws + (24u << 20));
    u16* Vtb   = (u16*)((char*)d_ws + (32u << 20));
    u16* yb    = (u16*)((char*)d_ws + (40u << 20));

    // 0) fp32 -> bf16 conversions (single dispatch)
    cvt3_kernel<<<8192, 256, 0, stream>>>(x, Wqkv, Wout, xb, wqkvb, woutb);

    // 1) QKV projection (128x128 tiles): 32 x 24 = 768 blocks
    gemm_tile_kernel<0><<<32 * (3 * D_MODEL / 128), 256, 0, stream>>>(
        xb, wqkvb, 3 * D_MODEL, D_MODEL, nullptr, Qb, Kb, Vtb);

    // 2) MFMA causal flash attention -> yb
    attn_mfma_kernel<<<B_SZ * N_HEADS * (T_SEQ / 64), 256, 0, stream>>>(Qb, Kb, Vtb, yb);

    // 3) Output projection (128x128 tiles): 32 x 8 = 256 blocks -> fp32 out
    gemm_tile_kernel<1><<<32 * (D_MODEL / 128), 256, 0, stream>>>(
        yb, woutb, D_MODEL, D_MODEL, out, nullptr, nullptr, nullptr);
}